// Round 1
// baseline (5602.048 us; speedup 1.0000x reference)
//
#include <hip/hip_runtime.h>
#include <math.h>

#define NN 100000
#define NE 1600000
#define DIM 64
#define W1T_STRIDE 132  // 129 padded to multiple of 4 for float4 loads

// ---------------- Kernel 0: transpose w1 (129x64) -> w1T (64 x 132) ----------------
__global__ __launch_bounds__(256) void prep_w1t(const float* __restrict__ w1,
                                                float* __restrict__ w1t) {
    int idx = blockIdx.x * 256 + threadIdx.x;
    if (idx >= 129 * 64) return;
    int k = idx / 64;   // 0..128
    int j = idx % 64;   // 0..63
    w1t[j * W1T_STRIDE + k] = w1[k * 64 + j];
}

// ---------------- Kernel 1: x_t = x @ wt + bt ----------------
__global__ __launch_bounds__(256) void transform_kernel(
    const float* __restrict__ x, const float* __restrict__ wt,
    const float* __restrict__ bt, float* __restrict__ xt) {
    __shared__ float wt_s[64 * 64];
    __shared__ float xrow[4][64];
    int t = threadIdx.x;
    for (int i = t; i < 64 * 64; i += 256) wt_s[i] = wt[i];
    int w = t >> 6;
    int lane = t & 63;
    int node = blockIdx.x * 4 + w;
    if (node < NN) xrow[w][lane] = x[node * 64 + lane];
    __syncthreads();
    if (node >= NN) return;
    float acc = bt[lane];
#pragma unroll
    for (int k = 0; k < 64; ++k)
        acc = fmaf(xrow[w][k], wt_s[k * 64 + lane], acc);
    xt[(size_t)node * 64 + lane] = acc;
}

// ---------------- Kernel 2: per-edge MLP + scatter ----------------
__global__ __launch_bounds__(256) void edge_kernel(
    const float* __restrict__ x, const int* __restrict__ ei,
    const float* __restrict__ pos,
    const float* __restrict__ w1t, const float* __restrict__ b1,
    const float* __restrict__ w2, const float* __restrict__ b2,
    const float* __restrict__ xt,
    float* __restrict__ out, float* __restrict__ ew_out) {
    int e = blockIdx.x * 256 + threadIdx.x;
    if (e >= NE) return;
    int src = ei[e];
    int dst = ei[NE + e];

    // load x[src], x[dst] into registers (float4 vectorized)
    float xs[64], xd[64];
    const float4* xsp = (const float4*)(x + (size_t)src * 64);
    const float4* xdp = (const float4*)(x + (size_t)dst * 64);
#pragma unroll
    for (int q = 0; q < 16; ++q) {
        float4 a = xsp[q];
        xs[4 * q + 0] = a.x; xs[4 * q + 1] = a.y; xs[4 * q + 2] = a.z; xs[4 * q + 3] = a.w;
        float4 b = xdp[q];
        xd[4 * q + 0] = b.x; xd[4 * q + 1] = b.y; xd[4 * q + 2] = b.z; xd[4 * q + 3] = b.w;
    }
    float dx = pos[dst * 3 + 0] - pos[src * 3 + 0];
    float dy = pos[dst * 3 + 1] - pos[src * 3 + 1];
    float dz = pos[dst * 3 + 2] - pos[src * 3 + 2];
    float len = sqrtf(dx * dx + dy * dy + dz * dz);

    // edge MLP: s = sum_j relu(b1[j] + feat . w1[:,j]) * w2[j]
    float s = 0.f;
    for (int j = 0; j < 64; ++j) {
        const float4* wrow = (const float4*)(w1t + j * W1T_STRIDE);  // uniform addr -> s_load
        float acc = b1[j];
#pragma unroll
        for (int q = 0; q < 16; ++q) {
            float4 wv = wrow[q];
            acc = fmaf(xs[4 * q + 0], wv.x, acc);
            acc = fmaf(xs[4 * q + 1], wv.y, acc);
            acc = fmaf(xs[4 * q + 2], wv.z, acc);
            acc = fmaf(xs[4 * q + 3], wv.w, acc);
        }
#pragma unroll
        for (int q = 0; q < 16; ++q) {
            float4 wv = wrow[16 + q];
            acc = fmaf(xd[4 * q + 0], wv.x, acc);
            acc = fmaf(xd[4 * q + 1], wv.y, acc);
            acc = fmaf(xd[4 * q + 2], wv.z, acc);
            acc = fmaf(xd[4 * q + 3], wv.w, acc);
        }
        acc = fmaf(len, w1t[j * W1T_STRIDE + 128], acc);
        s = fmaf(fmaxf(acc, 0.f), w2[j], s);
    }
    float z = s + b2[0];
    float ewv = 1.f / (1.f + __expf(-z));
    ew_out[e] = ewv;

    // scatter: out[dst] += x_t[src] * ew
    const float4* xtp = (const float4*)(xt + (size_t)src * 64);
    float* op = out + (size_t)dst * 64;
#pragma unroll
    for (int q = 0; q < 16; ++q) {
        float4 v = xtp[q];
        atomicAdd(op + 4 * q + 0, v.x * ewv);
        atomicAdd(op + 4 * q + 1, v.y * ewv);
        atomicAdd(op + 4 * q + 2, v.z * ewv);
        atomicAdd(op + 4 * q + 3, v.w * ewv);
    }
}

extern "C" void kernel_launch(void* const* d_in, const int* in_sizes, int n_in,
                              void* d_out, int out_size, void* d_ws, size_t ws_size,
                              hipStream_t stream) {
    const float* x   = (const float*)d_in[0];
    const int*   ei  = (const int*)d_in[1];
    const float* pos = (const float*)d_in[2];
    const float* w1  = (const float*)d_in[3];
    const float* b1  = (const float*)d_in[4];
    const float* w2  = (const float*)d_in[5];
    const float* b2  = (const float*)d_in[6];
    const float* wt  = (const float*)d_in[7];
    const float* bt  = (const float*)d_in[8];

    float* out    = (float*)d_out;            // [NN*64]
    float* ew_out = out + (size_t)NN * 64;    // [NE]

    // workspace layout: xt [NN*64 f32], then w1t [64*132 f32]
    float* xt  = (float*)d_ws;
    float* w1t = xt + (size_t)NN * 64;

    hipMemsetAsync(out, 0, (size_t)NN * 64 * sizeof(float), stream);
    prep_w1t<<<(129 * 64 + 255) / 256, 256, 0, stream>>>(w1, w1t);
    transform_kernel<<<(NN + 3) / 4, 256, 0, stream>>>(x, wt, bt, xt);
    edge_kernel<<<(NE + 255) / 256, 256, 0, stream>>>(x, ei, pos, w1t, b1, w2, b2,
                                                      xt, out, ew_out);
}

// Round 2
// 767.079 us; speedup vs baseline: 7.3031x; 7.3031x over previous
//
#include <hip/hip_runtime.h>
#include <math.h>

#define NN 100000
#define NE 1600000
#define DIM 64

// ---------------- Kernel 1: x_t = x @ wt + bt ----------------
__global__ __launch_bounds__(256) void transform_kernel(
    const float* __restrict__ x, const float* __restrict__ wt,
    const float* __restrict__ bt, float* __restrict__ xt) {
    __shared__ float wt_s[64 * 64];
    __shared__ float xrow[4][64];
    int t = threadIdx.x;
    for (int i = t; i < 64 * 64; i += 256) wt_s[i] = wt[i];
    int w = t >> 6;
    int lane = t & 63;
    int node = blockIdx.x * 4 + w;
    if (node < NN) xrow[w][lane] = x[node * 64 + lane];
    __syncthreads();
    if (node >= NN) return;
    float acc = bt[lane];
#pragma unroll
    for (int k = 0; k < 64; ++k)
        acc = fmaf(xrow[w][k], wt_s[k * 64 + lane], acc);
    xt[(size_t)node * 64 + lane] = acc;
}

// ---------------- Kernel 2: per-edge MLP -> edge weights ----------------
// thread-per-edge; acc[64] hidden pre-activations in VGPRs; features
// streamed in 16-float chunks; w1 rows read with wave-uniform addresses
// (scalarizable to s_load -> SGPR operand of v_fmac).
__global__ __launch_bounds__(256) void edge_mlp_kernel(
    const float* __restrict__ x, const int* __restrict__ ei,
    const float* __restrict__ pos,
    const float* __restrict__ w1, const float* __restrict__ b1,
    const float* __restrict__ w2, const float* __restrict__ b2,
    float* __restrict__ ew_out) {
    int e = blockIdx.x * 256 + threadIdx.x;
    if (e >= NE) return;
    int src = ei[e];
    int dst = ei[NE + e];

    float dx = pos[dst * 3 + 0] - pos[src * 3 + 0];
    float dy = pos[dst * 3 + 1] - pos[src * 3 + 1];
    float dz = pos[dst * 3 + 2] - pos[src * 3 + 2];
    float len = sqrtf(dx * dx + dy * dy + dz * dz);

    float acc[64];
#pragma unroll
    for (int j = 0; j < 64; ++j) acc[j] = b1[j];  // uniform -> scalar loads

    const float* xsrow = x + (size_t)src * 64;
    const float* xdrow = x + (size_t)dst * 64;

#pragma unroll 1
    for (int kc = 0; kc < 8; ++kc) {  // 8 chunks of 16 k's (4 src, 4 dst)
        const float* base = (kc < 4) ? xsrow : xdrow;
        int koff = (kc & 3) * 16;
        float f[16];
        const float4* bp = (const float4*)(base + koff);
#pragma unroll
        for (int q = 0; q < 4; ++q) {
            float4 v = bp[q];
            f[4 * q + 0] = v.x; f[4 * q + 1] = v.y;
            f[4 * q + 2] = v.z; f[4 * q + 3] = v.w;
        }
        const float* wbase = w1 + (size_t)(kc * 16) * 64;
#pragma unroll
        for (int i = 0; i < 16; ++i) {
            const float* wrow = wbase + i * 64;  // wave-uniform address
#pragma unroll
            for (int j = 0; j < 64; ++j)
                acc[j] = fmaf(f[i], wrow[j], acc[j]);
        }
    }
    // k = 128: edge length term
    {
        const float* wrow = w1 + 128 * 64;
#pragma unroll
        for (int j = 0; j < 64; ++j)
            acc[j] = fmaf(len, wrow[j], acc[j]);
    }
    // layer 2
    float s = b2[0];
#pragma unroll
    for (int j = 0; j < 64; ++j)
        s = fmaf(fmaxf(acc[j], 0.f), w2[j], s);
    ew_out[e] = 1.f / (1.f + __expf(-s));
}

// ---------------- Kernel 3: coalesced scatter ----------------
// wave per edge: lane q handles component q -> one atomic instruction
// touches 4 consecutive cache lines of a single dst row.
__global__ __launch_bounds__(256) void scatter_kernel(
    const int* __restrict__ ei, const float* __restrict__ ew,
    const float* __restrict__ xt, float* __restrict__ out) {
    long long idx = (long long)blockIdx.x * 256 + threadIdx.x;
    int e = (int)(idx >> 6);
    int lane = (int)(idx & 63);
    if (e >= NE) return;
    int src = ei[e];
    int dst = ei[NE + e];
    float w = ew[e];
    float v = xt[(size_t)src * 64 + lane] * w;
    atomicAdd(out + (size_t)dst * 64 + lane, v);
}

extern "C" void kernel_launch(void* const* d_in, const int* in_sizes, int n_in,
                              void* d_out, int out_size, void* d_ws, size_t ws_size,
                              hipStream_t stream) {
    const float* x   = (const float*)d_in[0];
    const int*   ei  = (const int*)d_in[1];
    const float* pos = (const float*)d_in[2];
    const float* w1  = (const float*)d_in[3];
    const float* b1  = (const float*)d_in[4];
    const float* w2  = (const float*)d_in[5];
    const float* b2  = (const float*)d_in[6];
    const float* wt  = (const float*)d_in[7];
    const float* bt  = (const float*)d_in[8];

    float* out    = (float*)d_out;            // [NN*64]
    float* ew_out = out + (size_t)NN * 64;    // [NE]

    float* xt = (float*)d_ws;                 // [NN*64]

    hipMemsetAsync(out, 0, (size_t)NN * 64 * sizeof(float), stream);
    transform_kernel<<<(NN + 3) / 4, 256, 0, stream>>>(x, wt, bt, xt);
    edge_mlp_kernel<<<(NE + 255) / 256, 256, 0, stream>>>(x, ei, pos, w1, b1,
                                                          w2, b2, ew_out);
    scatter_kernel<<<(int)(((long long)NE * 64 + 255) / 256), 256, 0, stream>>>(
        ei, ew_out, xt, out);
}

// Round 3
// 630.244 us; speedup vs baseline: 8.8887x; 1.2171x over previous
//
#include <hip/hip_runtime.h>
#include <hip/hip_bf16.h>
#include <math.h>

#define NN 100000
#define NE 1600000
#define DIM 64

typedef __attribute__((ext_vector_type(8))) short short8;
typedef __attribute__((ext_vector_type(4))) float floatx4;

static __device__ __forceinline__ unsigned short f2b(float f) {
    __hip_bfloat16 h = __float2bfloat16(f);
    return *(unsigned short*)&h;
}

// ---------------- prep: x -> bf16 ----------------
__global__ __launch_bounds__(256) void conv_x_kernel(const float* __restrict__ x,
                                                     unsigned short* __restrict__ xb) {
    int idx = blockIdx.x * 256 + threadIdx.x;   // one float4 per thread
    if (idx >= NN * DIM / 4) return;
    float4 v = ((const float4*)x)[idx];
    ushort4 o;
    o.x = f2b(v.x); o.y = f2b(v.y); o.z = f2b(v.z); o.w = f2b(v.w);
    ((ushort4*)xb)[idx] = o;
}

// ---------------- prep: w1[0:128][64] -> w1t bf16 [64][128] ----------------
__global__ __launch_bounds__(256) void prep_w1tb(const float* __restrict__ w1,
                                                 unsigned short* __restrict__ w1tb) {
    int idx = blockIdx.x * 256 + threadIdx.x;
    if (idx >= 64 * 128) return;
    int n = idx >> 7;
    int k = idx & 127;
    w1tb[n * 128 + k] = f2b(w1[k * 64 + n]);
}

// ---------------- Kernel 1: x_t = x @ wt + bt ----------------
__global__ __launch_bounds__(256) void transform_kernel(
    const float* __restrict__ x, const float* __restrict__ wt,
    const float* __restrict__ bt, float* __restrict__ xt) {
    __shared__ float wt_s[64 * 64];
    __shared__ float xrow[4][64];
    int t = threadIdx.x;
    for (int i = t; i < 64 * 64; i += 256) wt_s[i] = wt[i];
    int w = t >> 6;
    int lane = t & 63;
    int node = blockIdx.x * 4 + w;
    if (node < NN) xrow[w][lane] = x[node * 64 + lane];
    __syncthreads();
    if (node >= NN) return;
    float acc = bt[lane];
#pragma unroll
    for (int k = 0; k < 64; ++k)
        acc = fmaf(xrow[w][k], wt_s[k * 64 + lane], acc);
    xt[(size_t)node * 64 + lane] = acc;
}

// ---------------- Kernel 2: MFMA edge MLP ----------------
// Block = 256 threads (4 waves) = 64 edges. A[64][128] bf16 = [x_src|x_dst],
// B = w1t bf16 [64 hidden][128 k]. K=128 in MFMA; k=128 (length) + bias +
// relu + layer2 + sigmoid fused in epilogue.
#define APAD 136  // row stride in shorts: 272B = 68 dwords = 4 banks skew -> conflict-free
__global__ __launch_bounds__(256) void edge_mlp_mfma(
    const unsigned short* __restrict__ xb, const int* __restrict__ ei,
    const float* __restrict__ pos,
    const unsigned short* __restrict__ w1tb, const float* __restrict__ w1,
    const float* __restrict__ b1, const float* __restrict__ w2,
    const float* __restrict__ b2, float* __restrict__ ew_out) {
    __shared__ unsigned short As[64 * APAD];
    __shared__ unsigned short Bs[64 * APAD];
    __shared__ float len_s[64], b1_s[64], w2_s[64], wl_s[64];

    int t = threadIdx.x;
    int ebase = blockIdx.x * 64;

    // ---- stage A: 64 rows x 16 segs(16B); 4 threads per row ----
    {
        int r = t & 63;
        int s0 = t >> 6;
        int src = ei[ebase + r];
        int dst = ei[NE + ebase + r];
        const uint4* srow = (const uint4*)(xb + (size_t)src * 64);  // 8 segs
        const uint4* drow = (const uint4*)(xb + (size_t)dst * 64);
#pragma unroll
        for (int i = 0; i < 4; ++i) {
            int s = s0 + 4 * i;  // 0..15
            uint4 v = (s < 8) ? srow[s] : drow[s - 8];
            *(uint4*)&As[r * APAD + s * 8] = v;
        }
    }
    // ---- stage B: w1tb rows ----
    {
        int r = t & 63;
        int s0 = t >> 6;
        const uint4* wrow = (const uint4*)(w1tb + r * 128);  // 16 segs
#pragma unroll
        for (int i = 0; i < 4; ++i) {
            int s = s0 + 4 * i;
            *(uint4*)&Bs[r * APAD + s * 8] = wrow[s];
        }
    }
    // ---- stage scalars + edge length ----
    if (t < 64) {
        int src = ei[ebase + t];
        int dst = ei[NE + ebase + t];
        float dx = pos[dst * 3 + 0] - pos[src * 3 + 0];
        float dy = pos[dst * 3 + 1] - pos[src * 3 + 1];
        float dz = pos[dst * 3 + 2] - pos[src * 3 + 2];
        len_s[t] = sqrtf(dx * dx + dy * dy + dz * dz);
        b1_s[t] = b1[t];
        w2_s[t] = w2[t];
        wl_s[t] = w1[128 * 64 + t];
    }
    __syncthreads();

    int lane = t & 63;
    int wave = t >> 6;
    int grp = lane >> 4;
    int l15 = lane & 15;

    floatx4 acc[4] = {{0, 0, 0, 0}, {0, 0, 0, 0}, {0, 0, 0, 0}, {0, 0, 0, 0}};

    int arow = wave * 16 + l15;   // edge (m)
#pragma unroll
    for (int ks = 0; ks < 4; ++ks) {
        int koff = ks * 32 + grp * 8;
        short8 a = *(const short8*)&As[arow * APAD + koff];
#pragma unroll
        for (int nt = 0; nt < 4; ++nt) {
            short8 b = *(const short8*)&Bs[(nt * 16 + l15) * APAD + koff];
            acc[nt] = __builtin_amdgcn_mfma_f32_16x16x32_bf16(a, b, acc[nt], 0, 0, 0);
        }
    }

    // ---- epilogue: bias + length term + relu + layer2 dot + sigmoid ----
    float sr[4] = {0.f, 0.f, 0.f, 0.f};
#pragma unroll
    for (int nt = 0; nt < 4; ++nt) {
        int j = nt * 16 + l15;
        float b1v = b1_s[j];
        float w2v = w2_s[j];
        float wlv = wl_s[j];
#pragma unroll
        for (int r = 0; r < 4; ++r) {
            int el = wave * 16 + grp * 4 + r;   // edge (C row)
            float h = acc[nt][r] + b1v + len_s[el] * wlv;
            sr[r] = fmaf(fmaxf(h, 0.f), w2v, sr[r]);
        }
    }
#pragma unroll
    for (int r = 0; r < 4; ++r) {
#pragma unroll
        for (int off = 1; off < 16; off <<= 1)
            sr[r] += __shfl_xor(sr[r], off);
    }
    float b2v = b2[0];
    if (l15 == 0) {
#pragma unroll
        for (int r = 0; r < 4; ++r) {
            float s = sr[r] + b2v;
            ew_out[ebase + wave * 16 + grp * 4 + r] = 1.f / (1.f + __expf(-s));
        }
    }
}

// ---------------- Kernel 3: coalesced scatter ----------------
__global__ __launch_bounds__(256) void scatter_kernel(
    const int* __restrict__ ei, const float* __restrict__ ew,
    const float* __restrict__ xt, float* __restrict__ out) {
    long long idx = (long long)blockIdx.x * 256 + threadIdx.x;
    int e = (int)(idx >> 6);
    int lane = (int)(idx & 63);
    if (e >= NE) return;
    int src = ei[e];
    int dst = ei[NE + e];
    float w = ew[e];
    float v = xt[(size_t)src * 64 + lane] * w;
    atomicAdd(out + (size_t)dst * 64 + lane, v);
}

extern "C" void kernel_launch(void* const* d_in, const int* in_sizes, int n_in,
                              void* d_out, int out_size, void* d_ws, size_t ws_size,
                              hipStream_t stream) {
    const float* x   = (const float*)d_in[0];
    const int*   ei  = (const int*)d_in[1];
    const float* pos = (const float*)d_in[2];
    const float* w1  = (const float*)d_in[3];
    const float* b1  = (const float*)d_in[4];
    const float* w2  = (const float*)d_in[5];
    const float* b2  = (const float*)d_in[6];
    const float* wt  = (const float*)d_in[7];
    const float* bt  = (const float*)d_in[8];

    float* out    = (float*)d_out;            // [NN*64]
    float* ew_out = out + (size_t)NN * 64;    // [NE]

    // workspace: xt [NN*64 f32] | xb [NN*64 bf16] | w1tb [64*128 bf16]
    float* xt = (float*)d_ws;
    unsigned short* xb = (unsigned short*)(xt + (size_t)NN * 64);
    unsigned short* w1tb = xb + (size_t)NN * 64;

    hipMemsetAsync(out, 0, (size_t)NN * 64 * sizeof(float), stream);
    conv_x_kernel<<<(NN * DIM / 4 + 255) / 256, 256, 0, stream>>>(x, xb);
    prep_w1tb<<<(64 * 128 + 255) / 256, 256, 0, stream>>>(w1, w1tb);
    transform_kernel<<<(NN + 3) / 4, 256, 0, stream>>>(x, wt, bt, xt);
    edge_mlp_mfma<<<NE / 64, 256, 0, stream>>>(xb, ei, pos, w1tb, w1, b1, w2, b2,
                                               ew_out);
    scatter_kernel<<<(int)(((long long)NE * 64 + 255) / 256), 256, 0, stream>>>(
        ei, ew_out, xt, out);
}

// Round 4
// 624.117 us; speedup vs baseline: 8.9760x; 1.0098x over previous
//
#include <hip/hip_runtime.h>
#include <hip/hip_bf16.h>
#include <math.h>

#define NN 100000
#define NE 1600000
#define DIM 64

typedef __attribute__((ext_vector_type(8))) short short8;
typedef __attribute__((ext_vector_type(4))) float floatx4;

static __device__ __forceinline__ unsigned short f2b(float f) {
    __hip_bfloat16 h = __float2bfloat16(f);
    return *(unsigned short*)&h;
}

// ---------------- prep: x -> bf16 ----------------
__global__ __launch_bounds__(256) void conv_x_kernel(const float* __restrict__ x,
                                                     unsigned short* __restrict__ xb) {
    int idx = blockIdx.x * 256 + threadIdx.x;   // one float4 per thread
    if (idx >= NN * DIM / 4) return;
    float4 v = ((const float4*)x)[idx];
    ushort4 o;
    o.x = f2b(v.x); o.y = f2b(v.y); o.z = f2b(v.z); o.w = f2b(v.w);
    ((ushort4*)xb)[idx] = o;
}

// ---------------- prep: w1[0:128][64] -> w1t bf16 [64][128] ----------------
__global__ __launch_bounds__(256) void prep_w1tb(const float* __restrict__ w1,
                                                 unsigned short* __restrict__ w1tb) {
    int idx = blockIdx.x * 256 + threadIdx.x;
    if (idx >= 64 * 128) return;
    int n = idx >> 7;
    int k = idx & 127;
    w1tb[n * 128 + k] = f2b(w1[k * 64 + n]);
}

// ---------------- Kernel 1: x_t = x @ wt + bt ----------------
__global__ __launch_bounds__(256) void transform_kernel(
    const float* __restrict__ x, const float* __restrict__ wt,
    const float* __restrict__ bt, float* __restrict__ xt) {
    __shared__ float wt_s[64 * 64];
    __shared__ float xrow[4][64];
    int t = threadIdx.x;
    for (int i = t; i < 64 * 64; i += 256) wt_s[i] = wt[i];
    int w = t >> 6;
    int lane = t & 63;
    int node = blockIdx.x * 4 + w;
    if (node < NN) xrow[w][lane] = x[node * 64 + lane];
    __syncthreads();
    if (node >= NN) return;
    float acc = bt[lane];
#pragma unroll
    for (int k = 0; k < 64; ++k)
        acc = fmaf(xrow[w][k], wt_s[k * 64 + lane], acc);
    xt[(size_t)node * 64 + lane] = acc;
}

// ---------------- Kernel 2: MFMA edge MLP ----------------
#define APAD 136
__global__ __launch_bounds__(256) void edge_mlp_mfma(
    const unsigned short* __restrict__ xb, const int* __restrict__ ei,
    const float* __restrict__ pos,
    const unsigned short* __restrict__ w1tb, const float* __restrict__ w1,
    const float* __restrict__ b1, const float* __restrict__ w2,
    const float* __restrict__ b2, float* __restrict__ ew_out) {
    __shared__ unsigned short As[64 * APAD];
    __shared__ unsigned short Bs[64 * APAD];
    __shared__ float len_s[64], b1_s[64], w2_s[64], wl_s[64];

    int t = threadIdx.x;
    int ebase = blockIdx.x * 64;

    {
        int r = t & 63;
        int s0 = t >> 6;
        int src = ei[ebase + r];
        int dst = ei[NE + ebase + r];
        const uint4* srow = (const uint4*)(xb + (size_t)src * 64);
        const uint4* drow = (const uint4*)(xb + (size_t)dst * 64);
#pragma unroll
        for (int i = 0; i < 4; ++i) {
            int s = s0 + 4 * i;
            uint4 v = (s < 8) ? srow[s] : drow[s - 8];
            *(uint4*)&As[r * APAD + s * 8] = v;
        }
    }
    {
        int r = t & 63;
        int s0 = t >> 6;
        const uint4* wrow = (const uint4*)(w1tb + r * 128);
#pragma unroll
        for (int i = 0; i < 4; ++i) {
            int s = s0 + 4 * i;
            *(uint4*)&Bs[r * APAD + s * 8] = wrow[s];
        }
    }
    if (t < 64) {
        int src = ei[ebase + t];
        int dst = ei[NE + ebase + t];
        float dx = pos[dst * 3 + 0] - pos[src * 3 + 0];
        float dy = pos[dst * 3 + 1] - pos[src * 3 + 1];
        float dz = pos[dst * 3 + 2] - pos[src * 3 + 2];
        len_s[t] = sqrtf(dx * dx + dy * dy + dz * dz);
        b1_s[t] = b1[t];
        w2_s[t] = w2[t];
        wl_s[t] = w1[128 * 64 + t];
    }
    __syncthreads();

    int lane = t & 63;
    int wave = t >> 6;
    int grp = lane >> 4;
    int l15 = lane & 15;

    floatx4 acc[4] = {{0, 0, 0, 0}, {0, 0, 0, 0}, {0, 0, 0, 0}, {0, 0, 0, 0}};

    int arow = wave * 16 + l15;
#pragma unroll
    for (int ks = 0; ks < 4; ++ks) {
        int koff = ks * 32 + grp * 8;
        short8 a = *(const short8*)&As[arow * APAD + koff];
#pragma unroll
        for (int nt = 0; nt < 4; ++nt) {
            short8 b = *(const short8*)&Bs[(nt * 16 + l15) * APAD + koff];
            acc[nt] = __builtin_amdgcn_mfma_f32_16x16x32_bf16(a, b, acc[nt], 0, 0, 0);
        }
    }

    float sr[4] = {0.f, 0.f, 0.f, 0.f};
#pragma unroll
    for (int nt = 0; nt < 4; ++nt) {
        int j = nt * 16 + l15;
        float b1v = b1_s[j];
        float w2v = w2_s[j];
        float wlv = wl_s[j];
#pragma unroll
        for (int r = 0; r < 4; ++r) {
            int el = wave * 16 + grp * 4 + r;
            float h = acc[nt][r] + b1v + len_s[el] * wlv;
            sr[r] = fmaf(fmaxf(h, 0.f), w2v, sr[r]);
        }
    }
#pragma unroll
    for (int r = 0; r < 4; ++r) {
#pragma unroll
        for (int off = 1; off < 16; off <<= 1)
            sr[r] += __shfl_xor(sr[r], off);
    }
    float b2v = b2[0];
    if (l15 == 0) {
#pragma unroll
        for (int r = 0; r < 4; ++r) {
            float s = sr[r] + b2v;
            ew_out[ebase + wave * 16 + grp * 4 + r] = 1.f / (1.f + __expf(-s));
        }
    }
}

// ---------------- CSR build: count ----------------
__global__ __launch_bounds__(256) void count_kernel(const int* __restrict__ ei,
                                                    int* __restrict__ deg) {
    int e = blockIdx.x * 256 + threadIdx.x;
    if (e >= NE) return;
    atomicAdd(&deg[ei[NE + e]], 1);
}

// ---------------- CSR build: allocate segments (wave prefix + 1 atomic/wave) ----
__global__ __launch_bounds__(256) void alloc_kernel(const int* __restrict__ deg,
                                                    int* __restrict__ start,
                                                    int* __restrict__ cursor,
                                                    int* __restrict__ counter) {
    int n = blockIdx.x * 256 + threadIdx.x;
    int lane = threadIdx.x & 63;
    int d = (n < NN) ? deg[n] : 0;
    int incl = d;
#pragma unroll
    for (int off = 1; off < 64; off <<= 1) {
        int v = __shfl_up(incl, off);
        if (lane >= off) incl += v;
    }
    int excl = incl - d;
    int total = __shfl(incl, 63);
    int base = 0;
    if (lane == 63) base = atomicAdd(counter, total);
    base = __shfl(base, 63);
    if (n < NN) {
        start[n] = base + excl;
        cursor[n] = base + excl;
    }
}

// ---------------- CSR build: scatter (src, ew) pairs ----------------
__global__ __launch_bounds__(256) void build_kernel(const int* __restrict__ ei,
                                                    const float* __restrict__ ew,
                                                    int* __restrict__ cursor,
                                                    uint2* __restrict__ pairs) {
    int e = blockIdx.x * 256 + threadIdx.x;
    if (e >= NE) return;
    int dst = ei[NE + e];
    int p = atomicAdd(&cursor[dst], 1);
    uint2 pr;
    pr.x = (unsigned)ei[e];
    pr.y = __float_as_uint(ew[e]);
    pairs[p] = pr;
}

// ---------------- Segment sum: wave per node, no atomics ----------------
__global__ __launch_bounds__(256) void accum_kernel(const uint2* __restrict__ pairs,
                                                    const int* __restrict__ start,
                                                    const int* __restrict__ deg,
                                                    const float* __restrict__ xt,
                                                    float* __restrict__ out) {
    int node = blockIdx.x * 4 + (threadIdx.x >> 6);
    int lane = threadIdx.x & 63;
    if (node >= NN) return;
    int s = start[node];
    int d = deg[node];
    float acc = 0.f;
    for (int j = 0; j < d; ++j) {
        uint2 pr = pairs[s + j];               // broadcast (same addr all lanes)
        float w = __uint_as_float(pr.y);
        acc = fmaf(xt[(size_t)pr.x * 64 + lane], w, acc);
    }
    out[(size_t)node * 64 + lane] = acc;
}

extern "C" void kernel_launch(void* const* d_in, const int* in_sizes, int n_in,
                              void* d_out, int out_size, void* d_ws, size_t ws_size,
                              hipStream_t stream) {
    const float* x   = (const float*)d_in[0];
    const int*   ei  = (const int*)d_in[1];
    const float* pos = (const float*)d_in[2];
    const float* w1  = (const float*)d_in[3];
    const float* b1  = (const float*)d_in[4];
    const float* w2  = (const float*)d_in[5];
    const float* b2  = (const float*)d_in[6];
    const float* wt  = (const float*)d_in[7];
    const float* bt  = (const float*)d_in[8];

    float* out    = (float*)d_out;            // [NN*64]
    float* ew_out = out + (size_t)NN * 64;    // [NE]

    // workspace layout (8B-aligned chain):
    // xt [NN*64 f32] | xb [NN*64 bf16] | pairs [NE uint2] | w1tb [64*128 bf16]
    // | deg [NN] | start [NN] | cursor [NN] | counter [1]
    float* xt = (float*)d_ws;
    unsigned short* xb = (unsigned short*)(xt + (size_t)NN * 64);
    uint2* pairs = (uint2*)(xb + (size_t)NN * 64);
    unsigned short* w1tb = (unsigned short*)(pairs + (size_t)NE);
    int* deg = (int*)(w1tb + 64 * 128);
    int* start = deg + NN;
    int* cursor = start + NN;
    int* counter = cursor + NN;

    hipMemsetAsync(deg, 0, (NN + 1) * sizeof(int), stream);          // deg only
    hipMemsetAsync(counter, 0, sizeof(int), stream);

    conv_x_kernel<<<(NN * DIM / 4 + 255) / 256, 256, 0, stream>>>(x, xb);
    prep_w1tb<<<(64 * 128 + 255) / 256, 256, 0, stream>>>(w1, w1tb);
    transform_kernel<<<(NN + 3) / 4, 256, 0, stream>>>(x, wt, bt, xt);
    edge_mlp_mfma<<<NE / 64, 256, 0, stream>>>(xb, ei, pos, w1tb, w1, b1, w2, b2,
                                               ew_out);
    count_kernel<<<(NE + 255) / 256, 256, 0, stream>>>(ei, deg);
    alloc_kernel<<<(NN + 255) / 256, 256, 0, stream>>>(deg, start, cursor, counter);
    build_kernel<<<(NE + 255) / 256, 256, 0, stream>>>(ei, ew_out, cursor, pairs);
    accum_kernel<<<(NN + 3) / 4, 256, 0, stream>>>(pairs, start, deg, xt, out);
}